// Round 7
// baseline (8579.621 us; speedup 1.0000x reference)
//
#include <hip/hip_runtime.h>
#include <math.h>

// ---------------------------------------------------------------------------
// NCPDecoder: 3-cell CfC RNN, B=1024, T=256.
// Round 9->10: depth-4 register pipeline inside mv3 (R9 otherwise kept).
// R9 (7.77 ms bench / 9.31 ms prof): FETCH 77 MB (weights L2-resident),
// VGPR 84, phase ~36 us vs pipe floors {VALU 9, LDS 18, L2-stream 18} us.
// Across R5/R7/R9 the phase is stuck ~36-40 us with no pipe saturated ->
// pole = exposed L2 latency: depth-2 ping-pong gives only ~96 cyc between
// weight-quad issue and use (L2 ~200-300 cyc), and 2.5 waves/SIMD (grid-
// limited 1 WG/CU) cannot cover it. R8 proved the direction but spilled
// because launch_bounds pinned VGPR=84; R9 has ~120 free regs at the
// grid-fixed occupancy.
// R10: named depth-4 sets W0-3 / A0-3 (static indexing only), prefetch 4
// k4-rows ahead (~440 cyc issue->use). ~140 VGPR, NO launch_bounds pin.
// Cell2 K-depth padded 61->64 (zeros) so all NK4 % 4 == 0.
// Per-accumulator k-order and bias init unchanged -> identical numerics.
// Spill canary: FETCH_SIZE must stay ~77 MB; VGPR_Count expected 130-170.
// ---------------------------------------------------------------------------

namespace {
constexpr int kBatch = 1024;
constexpr int kT     = 256;
constexpr int kDIN   = 128;
constexpr int kUNITS = 512;
constexpr int kINTER = 269;
constexpr int kCMD   = 179;
constexpr int kMOTOR = 64;
constexpr int kOUT   = 64;

constexpr int kCAT0 = kDIN + kINTER;    // 397
constexpr int kCAT1 = kINTER + kCMD;    // 448
constexpr int kCAT2 = kCMD + kMOTOR;    // 243

// k4 depths, all multiples of 4 (depth-4 pipeline) ; LDS activation strides
constexpr int kNK40 = 100;              // ceil(397/4)
constexpr int kNK41 = 112;              // 448/4
constexpr int kNK42 = 64;               // ceil(243/4)=61 -> 64 (zero pad)
constexpr int kS0 = 400;                // 4*kNK40
constexpr int kS1 = 448;
constexpr int kS2 = 256;                // 4*kNK42 (pad zeroed)

// weight quads per cell, layout W[(k4*3 + c)*NH + u], c in {ff1,ff2,t}
constexpr int kQ0 = kNK40 * 3 * kINTER; // 80700
constexpr int kQ1 = kNK41 * 3 * kCMD;   // 60144
constexpr int kQ2 = kNK42 * 3 * kMOTOR; // 12288
constexpr int kQ  = kQ0 + kQ1 + kQ2;    // 153132
// biases: per cell [c][u], c in {ff1,ff2,ta+tb}
constexpr int kB0 = 3 * kINTER;         // 807
constexpr int kB1 = 3 * kCMD;           // 537
constexpr int kB2 = 3 * kMOTOR;         // 192
constexpr int kBCN = kB0 + kB1 + kB2;   // 1536
constexpr int kBCOff = kQ * 4;          // float offset of biases in ws

constexpr int kMT = 4;     // batch rows per WG
constexpr int kNT = 640;   // threads per WG (10 waves)

static_assert(kNK40 % 4 == 0 && kNK41 % 4 == 0 && kNK42 % 4 == 0, "depth4");
}  // namespace

// Mask element-width detection. mask0 row 0, columns 128..396 are the
// structurally all-true h-block (full = concat([m, ones(n_h,n_h)]) then .T).
__device__ __forceinline__ int detect_mask_mode(const void* m0) {
  const unsigned int* w = (const unsigned int*)m0;
  if (w[32] == 0x01010101u && w[33] == 0x01010101u &&
      w[34] == 0x01010101u && w[35] == 0x01010101u)
    return 0;  // uint8
  if (w[128] == 0x3F800000u && w[129] == 0x3F800000u && w[130] == 0x3F800000u)
    return 2;  // f32
  return 1;    // int32
}

__device__ __forceinline__ bool mask_at(const void* mk, int idx, int mode) {
  if (mode == 0) return ((const unsigned char*)mk)[idx] != 0;
  if (mode == 1) return ((const int*)mk)[idx] != 0;
  return ((const float*)mk)[idx] != 0.0f;
}

// ---------------------------------------------------------------------------
// Prep: packed masked/fused weights, layout W[cell][(k4*3+c)*NH + u] quads.
// k-padding entries are exact zeros. Biases: [cell][c*NH + u].
// ---------------------------------------------------------------------------
__global__ void prep_kernel(
    const void* __restrict__ m0_, const void* __restrict__ m1_,
    const void* __restrict__ m2_,
    const float* __restrict__ f1w0, const float* __restrict__ f2w0,
    const float* __restrict__ taw0, const float* __restrict__ tbw0,
    const float* __restrict__ f1w1, const float* __restrict__ f2w1,
    const float* __restrict__ taw1, const float* __restrict__ tbw1,
    const float* __restrict__ f1w2, const float* __restrict__ f2w2,
    const float* __restrict__ taw2, const float* __restrict__ tbw2,
    const float* __restrict__ f1b0, const float* __restrict__ f2b0,
    const float* __restrict__ tab0, const float* __restrict__ tbb0,
    const float* __restrict__ f1b1, const float* __restrict__ f2b1,
    const float* __restrict__ tab1, const float* __restrict__ tbb1,
    const float* __restrict__ f1b2, const float* __restrict__ f2b2,
    const float* __restrict__ tab2, const float* __restrict__ tbb2,
    float* __restrict__ ws) {
  int i = blockIdx.x * 256 + threadIdx.x;
  const int mode = detect_mask_mode(m0_);
  if (i < kQ) {
    int qi, nh, cat, baseq;
    const void* mk;
    const float *wf1, *wf2, *wta, *wtb;
    if (i < kQ0) {
      qi = i; nh = kINTER; cat = kCAT0; mk = m0_;
      wf1 = f1w0; wf2 = f2w0; wta = taw0; wtb = tbw0; baseq = 0;
    } else if (i < kQ0 + kQ1) {
      qi = i - kQ0; nh = kCMD; cat = kCAT1; mk = m1_;
      wf1 = f1w1; wf2 = f2w1; wta = taw1; wtb = tbw1; baseq = kQ0;
    } else {
      qi = i - kQ0 - kQ1; nh = kMOTOR; cat = kCAT2; mk = m2_;
      wf1 = f1w2; wf2 = f2w2; wta = taw2; wtb = tbw2; baseq = kQ0 + kQ1;
    }
    const int k4  = qi / (3 * nh);
    const int rem = qi % (3 * nh);
    const int c   = rem / nh;
    const int u   = rem % nh;
    float v[4];
#pragma unroll
    for (int kk = 0; kk < 4; ++kk) {
      const int k = k4 * 4 + kk;
      float r = 0.0f;
      if (k < cat) {
        if (c == 0) {
          r = mask_at(mk, u * cat + k, mode) ? wf1[u * cat + k] : 0.0f;
        } else if (c == 1) {
          r = mask_at(mk, u * cat + k, mode) ? wf2[u * cat + k] : 0.0f;
        } else {
          r = wta[u * cat + k] + wtb[u * cat + k];
        }
      }
      v[kk] = r;
    }
    ((float4*)ws)[baseq + qi] = make_float4(v[0], v[1], v[2], v[3]);
  } else if (i < kQ + kBCN) {
    int j = i - kQ;
    int nh;
    const float *bf1, *bf2, *bta, *btb;
    if (j < kB0) {
      nh = kINTER; bf1 = f1b0; bf2 = f2b0; bta = tab0; btb = tbb0;
    } else if (j < kB0 + kB1) {
      j -= kB0; nh = kCMD; bf1 = f1b1; bf2 = f2b1; bta = tab1; btb = tbb1;
    } else {
      j -= kB0 + kB1; nh = kMOTOR; bf1 = f1b2; bf2 = f2b2; bta = tab2;
      btb = tbb2;
    }
    const int c = j / nh, u = j % nh;
    float r;
    if (c == 0) r = bf1[u];
    else if (c == 1) r = bf2[u];
    else r = bta[u] + btb[u];
    ws[kBCOff + (i - kQ)] = r;
  }
}

// 48 FMAs per k4: 3 chunk-weights x 4 rows x 4 lanes of the quad.
__device__ __forceinline__ void fma3(const float4 (&w)[3],
                                     const float4 (&av)[kMT],
                                     float (&acc)[3][kMT]) {
#pragma unroll
  for (int r = 0; r < kMT; ++r) {
#pragma unroll
    for (int c = 0; c < 3; ++c) {
      acc[c][r] = fmaf(w[c].x, av[r].x, acc[c][r]);
      acc[c][r] = fmaf(w[c].y, av[r].y, acc[c][r]);
      acc[c][r] = fmaf(w[c].z, av[r].z, acc[c][r]);
      acc[c][r] = fmaf(w[c].w, av[r].w, acc[c][r]);
    }
  }
}

__device__ __forceinline__ float cfc_combine(float p1, float p2, float pt) {
  float f1 = tanhf(p1);
  float f2 = tanhf(p2);
  float ti = 1.0f / (1.0f + expf(-pt));
  return f1 + ti * (f2 - f1);
}

// One hidden unit u: three dots (ff1/ff2/t) over cat, kMT rows, combined
// in-register. Depth-4 named pipeline: W0-3 (weights, L2) and A0-3 (acts,
// LDS broadcast) prefetched 4 k4-rows ahead (~440 cyc issue->use). All
// register arrays statically indexed (rule: no runtime-indexed regs).
template <int NK4, int NH, int AST>
__device__ __forceinline__ void mv3(const float4* __restrict__ pw,  // wbase+u
                                    const float* __restrict__ a,
                                    const float* __restrict__ bias, // cell base
                                    int u, float (&v)[kMT]) {
  float acc[3][kMT];
#pragma unroll
  for (int c = 0; c < 3; ++c) {
    const float b = bias[c * NH + u];
#pragma unroll
    for (int r = 0; r < kMT; ++r) acc[c][r] = b;
  }
  float4 W0[3], W1[3], W2[3], W3[3];
  float4 A0[kMT], A1[kMT], A2[kMT], A3[kMT];
#define WLOAD(Wx, kk)                                                    \
  _Pragma("unroll") for (int c = 0; c < 3; ++c) Wx[c] =                  \
      pw[((kk) * 3 + c) * NH];
#define ALOAD(Ax, kk)                                                    \
  _Pragma("unroll") for (int r = 0; r < kMT; ++r) Ax[r] =                \
      *(const float4*)(a + r * AST + (kk) * 4);
  WLOAD(W0, 0) ALOAD(A0, 0)
  WLOAD(W1, 1) ALOAD(A1, 1)
  WLOAD(W2, 2) ALOAD(A2, 2)
  WLOAD(W3, 3) ALOAD(A3, 3)
  int k4 = 0;
#pragma unroll 1
  for (; k4 + 8 <= NK4; k4 += 4) {
    fma3(W0, A0, acc);
    WLOAD(W0, k4 + 4) ALOAD(A0, k4 + 4)
    fma3(W1, A1, acc);
    WLOAD(W1, k4 + 5) ALOAD(A1, k4 + 5)
    fma3(W2, A2, acc);
    WLOAD(W2, k4 + 6) ALOAD(A2, k4 + 6)
    fma3(W3, A3, acc);
    WLOAD(W3, k4 + 7) ALOAD(A3, k4 + 7)
  }
  // tail: last 4 k4-rows already resident
  fma3(W0, A0, acc);
  fma3(W1, A1, acc);
  fma3(W2, A2, acc);
  fma3(W3, A3, acc);
#undef WLOAD
#undef ALOAD
#pragma unroll
  for (int r = 0; r < kMT; ++r)
    v[r] = cfc_combine(acc[0][r], acc[1][r], acc[2][r]);
}

// ---------------------------------------------------------------------------
// Pipelined persistent kernel. Phase p: matvec c0@t=p / c1@t=p-1 / c2@t=p-2
// (fused combine, result in regs) + fc head t=p-3 on wave 9; barrier;
// write-back of results to xc + x(p+1) prefetch; barrier.
// Wave map (640 thr): waves 0-4 c0 (269u), 5-7 c1 (179u), 8 c2 (64u),
// 9 fc head / x prefetch.
// ---------------------------------------------------------------------------
__global__ __launch_bounds__(kNT) void ncp_main(
    const float* __restrict__ x, const float* __restrict__ hidden,
    const float* __restrict__ ws, const float* __restrict__ fcw,
    const float* __restrict__ fcb, float* __restrict__ out) {
  __shared__ __align__(16) float xc0[kMT][kS0];   // [x_t | h0 | pad0]
  __shared__ __align__(16) float xc1[kMT][kS1];   // [n0  | h1]
  __shared__ __align__(16) float xc2[kMT][kS2];   // [n1  | h2 | pad0]
  __shared__ float s_fcwT[64 * 64];               // fc_w transposed [m][o]
  __shared__ float s_bc[kBCN];
  __shared__ float s_fcb[64];

  const int tid = threadIdx.x;
  const int b0 = blockIdx.x * kMT;

  // zero xc (k-padding lanes must be 0.0f, not garbage: 0*NaN = NaN)
#pragma unroll
  for (int r = 0; r < kMT; ++r) {
    if (tid < kS0) xc0[r][tid] = 0.0f;
    if (tid < kS1) xc1[r][tid] = 0.0f;
    if (tid < kS2) xc2[r][tid] = 0.0f;
  }
  __syncthreads();
  // initial hidden state -> h slots
  for (int i = tid; i < kMT * kUNITS; i += kNT) {
    int r = i >> 9, u = i & 511;
    float v = hidden[(size_t)(b0 + r) * kUNITS + u];
    if (u < kINTER) xc0[r][kDIN + u] = v;
    else if (u < kINTER + kCMD) xc1[r][u] = v;  // layout offset == u
    else xc2[r][kCMD + (u - (kINTER + kCMD))] = v;
  }
  for (int i = tid; i < kBCN; i += kNT) s_bc[i] = ws[kBCOff + i];
  if (tid < 64) s_fcb[tid] = fcb[tid];
  for (int i = tid; i < 64 * 64; i += kNT) {
    int m = i >> 6, o = i & 63;
    s_fcwT[i] = fcw[o * 64 + m];
  }
  if (tid < 128) {  // stage x(0): 4 rows x 128 floats = 128 float4
    int r = tid >> 5, d4 = tid & 31;
    *(float4*)&xc0[r][d4 * 4] =
        *(const float4*)&x[(size_t)(b0 + r) * (kT * kDIN) + d4 * 4];
  }
  __syncthreads();

  const float4* wp0 = (const float4*)ws;
  const float4* wp1 = wp0 + kQ0;
  const float4* wp2 = wp1 + kQ1;

  for (int p = 0; p < kT + 3; ++p) {
    float v[kMT];
    // ================= matvec (+fused combine) + fc section ==============
    if (tid < 320) {
      if (p < kT && tid < kINTER)
        mv3<kNK40, kINTER, kS0>(wp0 + tid, &xc0[0][0], s_bc, tid, v);
    } else if (tid < 512) {
      const int u = tid - 320;
      if (p >= 1 && p <= kT && u < kCMD)
        mv3<kNK41, kCMD, kS1>(wp1 + u, &xc1[0][0], s_bc + kB0, u, v);
    } else if (tid < 576) {
      const int u = tid - 512;
      if (p >= 2 && p <= kT + 1)
        mv3<kNK42, kMOTOR, kS2>(wp2 + u, &xc2[0][0], s_bc + kB0 + kB1, u, v);
    } else {
      // wave 9: fc head for t = p-3; reads n2(t) written at phase p-1.
      if (p >= 3) {
        const int o = tid - 576;  // 0..63
        const int t_fc = p - 3;
        float a0 = s_fcb[o], a1 = a0, a2 = a0, a3 = a0;
        for (int m = 0; m < kMOTOR; ++m) {
          float w = s_fcwT[m * 64 + o];
          a0 = fmaf(xc2[0][kCMD + m], w, a0);
          a1 = fmaf(xc2[1][kCMD + m], w, a1);
          a2 = fmaf(xc2[2][kCMD + m], w, a2);
          a3 = fmaf(xc2[3][kCMD + m], w, a3);
        }
        size_t base = (size_t)b0 * (kT * kOUT) + (size_t)t_fc * kOUT + o;
        const size_t rstride = (size_t)kT * kOUT;
        out[base] = a0;
        out[base + rstride] = a1;
        out[base + 2 * rstride] = a2;
        out[base + 3 * rstride] = a3;
      }
    }
    __syncthreads();
    // ================= write-back + x prefetch section ===================
    if (tid < 320) {
      if (p < kT && tid < kINTER) {
#pragma unroll
        for (int r = 0; r < kMT; ++r) {
          xc1[r][tid] = v[r];          // input to c1 (next phase)
          xc0[r][kDIN + tid] = v[r];   // h0 for c0@p+1
        }
      }
    } else if (tid < 512) {
      const int u = tid - 320;
      if (p >= 1 && p <= kT && u < kCMD) {
#pragma unroll
        for (int r = 0; r < kMT; ++r) {
          xc2[r][u] = v[r];            // input to c2 (next phase)
          xc1[r][kINTER + u] = v[r];   // h1
        }
      }
    } else if (tid < 576) {
      const int u = tid - 512;
      if (p >= 2 && p <= kT + 1) {
#pragma unroll
        for (int r = 0; r < kMT; ++r)
          xc2[r][kCMD + u] = v[r];     // h2 == n2(t) -> fc head @p+1
      }
    } else {
      if (p + 1 < kT) {  // prefetch x(p+1): 128 quads on 64 threads
        const int i2 = tid - 576;  // 0..63
#pragma unroll
        for (int q = 0; q < 2; ++q) {
          const int idx = i2 + q * 64;
          const int r = idx >> 5, d4 = idx & 31;
          *(float4*)&xc0[r][d4 * 4] =
              *(const float4*)&x[(size_t)(b0 + r) * (kT * kDIN) +
                                 (size_t)(p + 1) * kDIN + d4 * 4];
        }
      }
    }
    __syncthreads();
  }

  // final hidden state: h0(255)/h1(255)/h2(255) are in the h slots
  const size_t hnoff = (size_t)kBatch * kT * kOUT;
  for (int i = tid; i < kMT * kUNITS; i += kNT) {
    int r = i >> 9, u = i & 511;
    float v;
    if (u < kINTER) v = xc0[r][kDIN + u];
    else if (u < kINTER + kCMD) v = xc1[r][u];
    else v = xc2[r][kCMD + (u - (kINTER + kCMD))];
    out[hnoff + (size_t)(b0 + r) * kUNITS + u] = v;
  }
}

// ---------------------------------------------------------------------------
extern "C" void kernel_launch(void* const* d_in, const int* in_sizes, int n_in,
                              void* d_out, int out_size, void* d_ws, size_t ws_size,
                              hipStream_t stream) {
  (void)in_sizes; (void)n_in; (void)out_size; (void)ws_size;
  const float* x = (const float*)d_in[0];
  const float* hidden = (const float*)d_in[1];
  const void* m0 = d_in[2];
  const void* m1 = d_in[3];
  const void* m2 = d_in[4];
  const float* f1w0 = (const float*)d_in[5];
  const float* f1b0 = (const float*)d_in[6];
  const float* f2w0 = (const float*)d_in[7];
  const float* f2b0 = (const float*)d_in[8];
  const float* taw0 = (const float*)d_in[9];
  const float* tab0 = (const float*)d_in[10];
  const float* tbw0 = (const float*)d_in[11];
  const float* tbb0 = (const float*)d_in[12];
  const float* f1w1 = (const float*)d_in[13];
  const float* f1b1 = (const float*)d_in[14];
  const float* f2w1 = (const float*)d_in[15];
  const float* f2b1 = (const float*)d_in[16];
  const float* taw1 = (const float*)d_in[17];
  const float* tab1 = (const float*)d_in[18];
  const float* tbw1 = (const float*)d_in[19];
  const float* tbb1 = (const float*)d_in[20];
  const float* f1w2 = (const float*)d_in[21];
  const float* f1b2 = (const float*)d_in[22];
  const float* f2w2 = (const float*)d_in[23];
  const float* f2b2 = (const float*)d_in[24];
  const float* taw2 = (const float*)d_in[25];
  const float* tab2 = (const float*)d_in[26];
  const float* tbw2 = (const float*)d_in[27];
  const float* tbb2 = (const float*)d_in[28];
  const float* fcw = (const float*)d_in[29];
  const float* fcb = (const float*)d_in[30];
  float* ws = (float*)d_ws;
  float* out = (float*)d_out;

  const int prep_items = kQ + kBCN;  // 154668
  prep_kernel<<<(prep_items + 255) / 256, 256, 0, stream>>>(
      m0, m1, m2,
      f1w0, f2w0, taw0, tbw0,
      f1w1, f2w1, taw1, tbw1,
      f1w2, f2w2, taw2, tbw2,
      f1b0, f2b0, tab0, tbb0,
      f1b1, f2b1, tab1, tbb1,
      f1b2, f2b2, tab2, tbb2,
      ws);

  ncp_main<<<kBatch / kMT, kNT, 0, stream>>>(x, hidden, ws, fcw, fcb, out);
}

// Round 8
// 8502.153 us; speedup vs baseline: 1.0091x; 1.0091x over previous
//
#include <hip/hip_runtime.h>
#include <math.h>

// ---------------------------------------------------------------------------
// NCPDecoder: 3-cell CfC RNN, B=1024, T=256.
// Round 10->11: SAME code as R10, plus amdgpu_waves_per_eu(3,3).
// History: R9 (7.77/9.31 ms) depth-2, VGPR 84, phase ~36us vs ~18us floors
// -> exposed L2 latency. R10 added a depth-4 register pipeline but the
// allocator AGAIN capped VGPR at 84 (6 waves/EU heuristic; launch_bounds'
// 2nd arg is only a floor guarantee) -> state spilled to scratch (FETCH
// 77MB -> 2.7GB, 10.2 ms prof). R8 was the same failure at (768,3).
// R11: __attribute__((amdgpu_waves_per_eu(3,3))) sets the occupancy TARGET
// to 3 waves/EU -> VGPR budget ~170: depth-4 state (~140-150) fits, and the
// 10-wave WG still launches (3/3/2/2 per SIMD, 3x170 <= 512).
// Canaries: VGPR_Count must jump to ~130-168; FETCH_SIZE back to ~77 MB.
// Per-accumulator k-order and bias init unchanged -> identical numerics.
// ---------------------------------------------------------------------------

namespace {
constexpr int kBatch = 1024;
constexpr int kT     = 256;
constexpr int kDIN   = 128;
constexpr int kUNITS = 512;
constexpr int kINTER = 269;
constexpr int kCMD   = 179;
constexpr int kMOTOR = 64;
constexpr int kOUT   = 64;

constexpr int kCAT0 = kDIN + kINTER;    // 397
constexpr int kCAT1 = kINTER + kCMD;    // 448
constexpr int kCAT2 = kCMD + kMOTOR;    // 243

// k4 depths, all multiples of 4 (depth-4 pipeline) ; LDS activation strides
constexpr int kNK40 = 100;              // ceil(397/4)
constexpr int kNK41 = 112;              // 448/4
constexpr int kNK42 = 64;               // ceil(243/4)=61 -> 64 (zero pad)
constexpr int kS0 = 400;                // 4*kNK40
constexpr int kS1 = 448;
constexpr int kS2 = 256;                // 4*kNK42 (pad zeroed)

// weight quads per cell, layout W[(k4*3 + c)*NH + u], c in {ff1,ff2,t}
constexpr int kQ0 = kNK40 * 3 * kINTER; // 80700
constexpr int kQ1 = kNK41 * 3 * kCMD;   // 60144
constexpr int kQ2 = kNK42 * 3 * kMOTOR; // 12288
constexpr int kQ  = kQ0 + kQ1 + kQ2;    // 153132
// biases: per cell [c][u], c in {ff1,ff2,ta+tb}
constexpr int kB0 = 3 * kINTER;         // 807
constexpr int kB1 = 3 * kCMD;           // 537
constexpr int kB2 = 3 * kMOTOR;         // 192
constexpr int kBCN = kB0 + kB1 + kB2;   // 1536
constexpr int kBCOff = kQ * 4;          // float offset of biases in ws

constexpr int kMT = 4;     // batch rows per WG
constexpr int kNT = 640;   // threads per WG (10 waves)

static_assert(kNK40 % 4 == 0 && kNK41 % 4 == 0 && kNK42 % 4 == 0, "depth4");
}  // namespace

// Mask element-width detection. mask0 row 0, columns 128..396 are the
// structurally all-true h-block (full = concat([m, ones(n_h,n_h)]) then .T).
__device__ __forceinline__ int detect_mask_mode(const void* m0) {
  const unsigned int* w = (const unsigned int*)m0;
  if (w[32] == 0x01010101u && w[33] == 0x01010101u &&
      w[34] == 0x01010101u && w[35] == 0x01010101u)
    return 0;  // uint8
  if (w[128] == 0x3F800000u && w[129] == 0x3F800000u && w[130] == 0x3F800000u)
    return 2;  // f32
  return 1;    // int32
}

__device__ __forceinline__ bool mask_at(const void* mk, int idx, int mode) {
  if (mode == 0) return ((const unsigned char*)mk)[idx] != 0;
  if (mode == 1) return ((const int*)mk)[idx] != 0;
  return ((const float*)mk)[idx] != 0.0f;
}

// ---------------------------------------------------------------------------
// Prep: packed masked/fused weights, layout W[cell][(k4*3+c)*NH + u] quads.
// k-padding entries are exact zeros. Biases: [cell][c*NH + u].
// ---------------------------------------------------------------------------
__global__ void prep_kernel(
    const void* __restrict__ m0_, const void* __restrict__ m1_,
    const void* __restrict__ m2_,
    const float* __restrict__ f1w0, const float* __restrict__ f2w0,
    const float* __restrict__ taw0, const float* __restrict__ tbw0,
    const float* __restrict__ f1w1, const float* __restrict__ f2w1,
    const float* __restrict__ taw1, const float* __restrict__ tbw1,
    const float* __restrict__ f1w2, const float* __restrict__ f2w2,
    const float* __restrict__ taw2, const float* __restrict__ tbw2,
    const float* __restrict__ f1b0, const float* __restrict__ f2b0,
    const float* __restrict__ tab0, const float* __restrict__ tbb0,
    const float* __restrict__ f1b1, const float* __restrict__ f2b1,
    const float* __restrict__ tab1, const float* __restrict__ tbb1,
    const float* __restrict__ f1b2, const float* __restrict__ f2b2,
    const float* __restrict__ tab2, const float* __restrict__ tbb2,
    float* __restrict__ ws) {
  int i = blockIdx.x * 256 + threadIdx.x;
  const int mode = detect_mask_mode(m0_);
  if (i < kQ) {
    int qi, nh, cat, baseq;
    const void* mk;
    const float *wf1, *wf2, *wta, *wtb;
    if (i < kQ0) {
      qi = i; nh = kINTER; cat = kCAT0; mk = m0_;
      wf1 = f1w0; wf2 = f2w0; wta = taw0; wtb = tbw0; baseq = 0;
    } else if (i < kQ0 + kQ1) {
      qi = i - kQ0; nh = kCMD; cat = kCAT1; mk = m1_;
      wf1 = f1w1; wf2 = f2w1; wta = taw1; wtb = tbw1; baseq = kQ0;
    } else {
      qi = i - kQ0 - kQ1; nh = kMOTOR; cat = kCAT2; mk = m2_;
      wf1 = f1w2; wf2 = f2w2; wta = taw2; wtb = tbw2; baseq = kQ0 + kQ1;
    }
    const int k4  = qi / (3 * nh);
    const int rem = qi % (3 * nh);
    const int c   = rem / nh;
    const int u   = rem % nh;
    float v[4];
#pragma unroll
    for (int kk = 0; kk < 4; ++kk) {
      const int k = k4 * 4 + kk;
      float r = 0.0f;
      if (k < cat) {
        if (c == 0) {
          r = mask_at(mk, u * cat + k, mode) ? wf1[u * cat + k] : 0.0f;
        } else if (c == 1) {
          r = mask_at(mk, u * cat + k, mode) ? wf2[u * cat + k] : 0.0f;
        } else {
          r = wta[u * cat + k] + wtb[u * cat + k];
        }
      }
      v[kk] = r;
    }
    ((float4*)ws)[baseq + qi] = make_float4(v[0], v[1], v[2], v[3]);
  } else if (i < kQ + kBCN) {
    int j = i - kQ;
    int nh;
    const float *bf1, *bf2, *bta, *btb;
    if (j < kB0) {
      nh = kINTER; bf1 = f1b0; bf2 = f2b0; bta = tab0; btb = tbb0;
    } else if (j < kB0 + kB1) {
      j -= kB0; nh = kCMD; bf1 = f1b1; bf2 = f2b1; bta = tab1; btb = tbb1;
    } else {
      j -= kB0 + kB1; nh = kMOTOR; bf1 = f1b2; bf2 = f2b2; bta = tab2;
      btb = tbb2;
    }
    const int c = j / nh, u = j % nh;
    float r;
    if (c == 0) r = bf1[u];
    else if (c == 1) r = bf2[u];
    else r = bta[u] + btb[u];
    ws[kBCOff + (i - kQ)] = r;
  }
}

// 48 FMAs per k4: 3 chunk-weights x 4 rows x 4 lanes of the quad.
__device__ __forceinline__ void fma3(const float4 (&w)[3],
                                     const float4 (&av)[kMT],
                                     float (&acc)[3][kMT]) {
#pragma unroll
  for (int r = 0; r < kMT; ++r) {
#pragma unroll
    for (int c = 0; c < 3; ++c) {
      acc[c][r] = fmaf(w[c].x, av[r].x, acc[c][r]);
      acc[c][r] = fmaf(w[c].y, av[r].y, acc[c][r]);
      acc[c][r] = fmaf(w[c].z, av[r].z, acc[c][r]);
      acc[c][r] = fmaf(w[c].w, av[r].w, acc[c][r]);
    }
  }
}

__device__ __forceinline__ float cfc_combine(float p1, float p2, float pt) {
  float f1 = tanhf(p1);
  float f2 = tanhf(p2);
  float ti = 1.0f / (1.0f + expf(-pt));
  return f1 + ti * (f2 - f1);
}

// One hidden unit u: three dots (ff1/ff2/t) over cat, kMT rows, combined
// in-register. Depth-4 named pipeline: W0-3 (weights, L2) and A0-3 (acts,
// LDS broadcast) prefetched 4 k4-rows ahead (~440 cyc issue->use). All
// register arrays statically indexed (rule: no runtime-indexed regs).
template <int NK4, int NH, int AST>
__device__ __forceinline__ void mv3(const float4* __restrict__ pw,  // wbase+u
                                    const float* __restrict__ a,
                                    const float* __restrict__ bias, // cell base
                                    int u, float (&v)[kMT]) {
  float acc[3][kMT];
#pragma unroll
  for (int c = 0; c < 3; ++c) {
    const float b = bias[c * NH + u];
#pragma unroll
    for (int r = 0; r < kMT; ++r) acc[c][r] = b;
  }
  float4 W0[3], W1[3], W2[3], W3[3];
  float4 A0[kMT], A1[kMT], A2[kMT], A3[kMT];
#define WLOAD(Wx, kk)                                                    \
  _Pragma("unroll") for (int c = 0; c < 3; ++c) Wx[c] =                  \
      pw[((kk) * 3 + c) * NH];
#define ALOAD(Ax, kk)                                                    \
  _Pragma("unroll") for (int r = 0; r < kMT; ++r) Ax[r] =                \
      *(const float4*)(a + r * AST + (kk) * 4);
  WLOAD(W0, 0) ALOAD(A0, 0)
  WLOAD(W1, 1) ALOAD(A1, 1)
  WLOAD(W2, 2) ALOAD(A2, 2)
  WLOAD(W3, 3) ALOAD(A3, 3)
  int k4 = 0;
#pragma unroll 1
  for (; k4 + 8 <= NK4; k4 += 4) {
    fma3(W0, A0, acc);
    WLOAD(W0, k4 + 4) ALOAD(A0, k4 + 4)
    fma3(W1, A1, acc);
    WLOAD(W1, k4 + 5) ALOAD(A1, k4 + 5)
    fma3(W2, A2, acc);
    WLOAD(W2, k4 + 6) ALOAD(A2, k4 + 6)
    fma3(W3, A3, acc);
    WLOAD(W3, k4 + 7) ALOAD(A3, k4 + 7)
  }
  // tail: last 4 k4-rows already resident
  fma3(W0, A0, acc);
  fma3(W1, A1, acc);
  fma3(W2, A2, acc);
  fma3(W3, A3, acc);
#undef WLOAD
#undef ALOAD
#pragma unroll
  for (int r = 0; r < kMT; ++r)
    v[r] = cfc_combine(acc[0][r], acc[1][r], acc[2][r]);
}

// ---------------------------------------------------------------------------
// Pipelined persistent kernel. Phase p: matvec c0@t=p / c1@t=p-1 / c2@t=p-2
// (fused combine, result in regs) + fc head t=p-3 on wave 9; barrier;
// write-back of results to xc + x(p+1) prefetch; barrier.
// Wave map (640 thr): waves 0-4 c0 (269u), 5-7 c1 (179u), 8 c2 (64u),
// 9 fc head / x prefetch.
// amdgpu_waves_per_eu(3,3): occupancy target 3 waves/EU -> VGPR budget ~170
// so the depth-4 pipeline materializes in registers instead of scratch.
// ---------------------------------------------------------------------------
__global__ __launch_bounds__(kNT)
__attribute__((amdgpu_waves_per_eu(3, 3))) void ncp_main(
    const float* __restrict__ x, const float* __restrict__ hidden,
    const float* __restrict__ ws, const float* __restrict__ fcw,
    const float* __restrict__ fcb, float* __restrict__ out) {
  __shared__ __align__(16) float xc0[kMT][kS0];   // [x_t | h0 | pad0]
  __shared__ __align__(16) float xc1[kMT][kS1];   // [n0  | h1]
  __shared__ __align__(16) float xc2[kMT][kS2];   // [n1  | h2 | pad0]
  __shared__ float s_fcwT[64 * 64];               // fc_w transposed [m][o]
  __shared__ float s_bc[kBCN];
  __shared__ float s_fcb[64];

  const int tid = threadIdx.x;
  const int b0 = blockIdx.x * kMT;

  // zero xc (k-padding lanes must be 0.0f, not garbage: 0*NaN = NaN)
#pragma unroll
  for (int r = 0; r < kMT; ++r) {
    if (tid < kS0) xc0[r][tid] = 0.0f;
    if (tid < kS1) xc1[r][tid] = 0.0f;
    if (tid < kS2) xc2[r][tid] = 0.0f;
  }
  __syncthreads();
  // initial hidden state -> h slots
  for (int i = tid; i < kMT * kUNITS; i += kNT) {
    int r = i >> 9, u = i & 511;
    float v = hidden[(size_t)(b0 + r) * kUNITS + u];
    if (u < kINTER) xc0[r][kDIN + u] = v;
    else if (u < kINTER + kCMD) xc1[r][u] = v;  // layout offset == u
    else xc2[r][kCMD + (u - (kINTER + kCMD))] = v;
  }
  for (int i = tid; i < kBCN; i += kNT) s_bc[i] = ws[kBCOff + i];
  if (tid < 64) s_fcb[tid] = fcb[tid];
  for (int i = tid; i < 64 * 64; i += kNT) {
    int m = i >> 6, o = i & 63;
    s_fcwT[i] = fcw[o * 64 + m];
  }
  if (tid < 128) {  // stage x(0): 4 rows x 128 floats = 128 float4
    int r = tid >> 5, d4 = tid & 31;
    *(float4*)&xc0[r][d4 * 4] =
        *(const float4*)&x[(size_t)(b0 + r) * (kT * kDIN) + d4 * 4];
  }
  __syncthreads();

  const float4* wp0 = (const float4*)ws;
  const float4* wp1 = wp0 + kQ0;
  const float4* wp2 = wp1 + kQ1;

  for (int p = 0; p < kT + 3; ++p) {
    float v[kMT];
    // ================= matvec (+fused combine) + fc section ==============
    if (tid < 320) {
      if (p < kT && tid < kINTER)
        mv3<kNK40, kINTER, kS0>(wp0 + tid, &xc0[0][0], s_bc, tid, v);
    } else if (tid < 512) {
      const int u = tid - 320;
      if (p >= 1 && p <= kT && u < kCMD)
        mv3<kNK41, kCMD, kS1>(wp1 + u, &xc1[0][0], s_bc + kB0, u, v);
    } else if (tid < 576) {
      const int u = tid - 512;
      if (p >= 2 && p <= kT + 1)
        mv3<kNK42, kMOTOR, kS2>(wp2 + u, &xc2[0][0], s_bc + kB0 + kB1, u, v);
    } else {
      // wave 9: fc head for t = p-3; reads n2(t) written at phase p-1.
      if (p >= 3) {
        const int o = tid - 576;  // 0..63
        const int t_fc = p - 3;
        float a0 = s_fcb[o], a1 = a0, a2 = a0, a3 = a0;
        for (int m = 0; m < kMOTOR; ++m) {
          float w = s_fcwT[m * 64 + o];
          a0 = fmaf(xc2[0][kCMD + m], w, a0);
          a1 = fmaf(xc2[1][kCMD + m], w, a1);
          a2 = fmaf(xc2[2][kCMD + m], w, a2);
          a3 = fmaf(xc2[3][kCMD + m], w, a3);
        }
        size_t base = (size_t)b0 * (kT * kOUT) + (size_t)t_fc * kOUT + o;
        const size_t rstride = (size_t)kT * kOUT;
        out[base] = a0;
        out[base + rstride] = a1;
        out[base + 2 * rstride] = a2;
        out[base + 3 * rstride] = a3;
      }
    }
    __syncthreads();
    // ================= write-back + x prefetch section ===================
    if (tid < 320) {
      if (p < kT && tid < kINTER) {
#pragma unroll
        for (int r = 0; r < kMT; ++r) {
          xc1[r][tid] = v[r];          // input to c1 (next phase)
          xc0[r][kDIN + tid] = v[r];   // h0 for c0@p+1
        }
      }
    } else if (tid < 512) {
      const int u = tid - 320;
      if (p >= 1 && p <= kT && u < kCMD) {
#pragma unroll
        for (int r = 0; r < kMT; ++r) {
          xc2[r][u] = v[r];            // input to c2 (next phase)
          xc1[r][kINTER + u] = v[r];   // h1
        }
      }
    } else if (tid < 576) {
      const int u = tid - 512;
      if (p >= 2 && p <= kT + 1) {
#pragma unroll
        for (int r = 0; r < kMT; ++r)
          xc2[r][kCMD + u] = v[r];     // h2 == n2(t) -> fc head @p+1
      }
    } else {
      if (p + 1 < kT) {  // prefetch x(p+1): 128 quads on 64 threads
        const int i2 = tid - 576;  // 0..63
#pragma unroll
        for (int q = 0; q < 2; ++q) {
          const int idx = i2 + q * 64;
          const int r = idx >> 5, d4 = idx & 31;
          *(float4*)&xc0[r][d4 * 4] =
              *(const float4*)&x[(size_t)(b0 + r) * (kT * kDIN) +
                                 (size_t)(p + 1) * kDIN + d4 * 4];
        }
      }
    }
    __syncthreads();
  }

  // final hidden state: h0(255)/h1(255)/h2(255) are in the h slots
  const size_t hnoff = (size_t)kBatch * kT * kOUT;
  for (int i = tid; i < kMT * kUNITS; i += kNT) {
    int r = i >> 9, u = i & 511;
    float v;
    if (u < kINTER) v = xc0[r][kDIN + u];
    else if (u < kINTER + kCMD) v = xc1[r][u];
    else v = xc2[r][kCMD + (u - (kINTER + kCMD))];
    out[hnoff + (size_t)(b0 + r) * kUNITS + u] = v;
  }
}

// ---------------------------------------------------------------------------
extern "C" void kernel_launch(void* const* d_in, const int* in_sizes, int n_in,
                              void* d_out, int out_size, void* d_ws, size_t ws_size,
                              hipStream_t stream) {
  (void)in_sizes; (void)n_in; (void)out_size; (void)ws_size;
  const float* x = (const float*)d_in[0];
  const float* hidden = (const float*)d_in[1];
  const void* m0 = d_in[2];
  const void* m1 = d_in[3];
  const void* m2 = d_in[4];
  const float* f1w0 = (const float*)d_in[5];
  const float* f1b0 = (const float*)d_in[6];
  const float* f2w0 = (const float*)d_in[7];
  const float* f2b0 = (const float*)d_in[8];
  const float* taw0 = (const float*)d_in[9];
  const float* tab0 = (const float*)d_in[10];
  const float* tbw0 = (const float*)d_in[11];
  const float* tbb0 = (const float*)d_in[12];
  const float* f1w1 = (const float*)d_in[13];
  const float* f1b1 = (const float*)d_in[14];
  const float* f2w1 = (const float*)d_in[15];
  const float* f2b1 = (const float*)d_in[16];
  const float* taw1 = (const float*)d_in[17];
  const float* tab1 = (const float*)d_in[18];
  const float* tbw1 = (const float*)d_in[19];
  const float* tbb1 = (const float*)d_in[20];
  const float* f1w2 = (const float*)d_in[21];
  const float* f1b2 = (const float*)d_in[22];
  const float* f2w2 = (const float*)d_in[23];
  const float* f2b2 = (const float*)d_in[24];
  const float* taw2 = (const float*)d_in[25];
  const float* tab2 = (const float*)d_in[26];
  const float* tbw2 = (const float*)d_in[27];
  const float* tbb2 = (const float*)d_in[28];
  const float* fcw = (const float*)d_in[29];
  const float* fcb = (const float*)d_in[30];
  float* ws = (float*)d_ws;
  float* out = (float*)d_out;

  const int prep_items = kQ + kBCN;  // 154668
  prep_kernel<<<(prep_items + 255) / 256, 256, 0, stream>>>(
      m0, m1, m2,
      f1w0, f2w0, taw0, tbw0,
      f1w1, f2w1, taw1, tbw1,
      f1w2, f2w2, taw2, tbw2,
      f1b0, f2b0, tab0, tbb0,
      f1b1, f2b1, tab1, tbb1,
      f1b2, f2b2, tab2, tbb2,
      ws);

  ncp_main<<<kBatch / kMT, kNT, 0, stream>>>(x, hidden, ws, fcw, fcb, out);
}